// Round 4
// baseline (239.302 us; speedup 1.0000x reference)
//
#include <hip/hip_runtime.h>
#include <hip/hip_bf16.h>

#define C_IN   256
#define C_OUT  512
#define NFILT  4

#define BM 128
#define BN 128
#define BK 32
#define SAS 40   // old-path LDS row stride

// fast path geometry: 32 bf16 per K-step, 8 steps, double-buffered
#define NSTEP 8

typedef __attribute__((ext_vector_type(8))) short bf16x8;
typedef __attribute__((ext_vector_type(4))) float floatx4;

union Pack8 { uint4 u; __hip_bfloat16 h[8]; };

// ---- bucketize: per-block LDS histogram, 4 global atomics per block ----
__global__ __launch_bounds__(1024) void bucketize_kernel(
    const float* __restrict__ xyz, int* __restrict__ idxbuf,
    int* __restrict__ cnt, int P)
{
    __shared__ int hist[NFILT];        // block totals
    __shared__ int wbase[16][NFILT];   // per-wave base within block
    __shared__ int gbase[NFILT];       // block's global base per filter

    int tid = threadIdx.x;
    int wid = tid >> 6;
    int lane = tid & 63;
    if (tid < NFILT) hist[tid] = 0;
    __syncthreads();

    int pid = blockIdx.x * 1024 + tid;
    int filt = -1;
    if (pid < P) {
        float x = xyz[pid * 3 + 0];
        float y = xyz[pid * 3 + 1];
        float z = xyz[pid * 3 + 2];
        // match np: non-fused fp32 sum of squares, then sqrt, then strict <
        float r2 = __fadd_rn(__fadd_rn(__fmul_rn(x, x), __fmul_rn(y, y)), __fmul_rn(z, z));
        float r = sqrtf(r2);
        if (r < 1.0f)        filt = 0;
        else if (r < 1.5f)   filt = 1;
        else if (r < 2.0f)   filt = 2;
        else if (r < 100.0f) filt = 3;
        else                 filt = 0;   // argmax over all-false booleans returns 0
    }

    int myoff = 0;
#pragma unroll
    for (int f = 0; f < NFILT; ++f) {
        unsigned long long m = __ballot(filt == f);
        if (lane == 0) wbase[wid][f] = atomicAdd(&hist[f], (int)__popcll(m));
        if (filt == f) myoff = __popcll(m & ((1ull << lane) - 1ull));
    }
    __syncthreads();
    if (tid < NFILT) gbase[tid] = atomicAdd(&cnt[tid], hist[tid]);
    __syncthreads();

    if (filt >= 0)
        idxbuf[filt * P + gbase[filt] + wbase[wid][filt] + myoff] = pid;
}

// also zeroes cnt (runs before bucketize on the same stream)
__global__ void convert_w_kernel(const float* __restrict__ w,
                                 ushort* __restrict__ wb,
                                 int* __restrict__ cnt) {
    if (blockIdx.x == 0 && threadIdx.x < NFILT) cnt[threadIdx.x] = 0;
    int i = (blockIdx.x * blockDim.x + threadIdx.x) * 4;
    float4 v = *(const float4*)(w + i);
    union { ushort4 u; __hip_bfloat16 h[4]; } cv;
    cv.h[0] = __float2bfloat16(v.x);
    cv.h[1] = __float2bfloat16(v.y);
    cv.h[2] = __float2bfloat16(v.z);
    cv.h[3] = __float2bfloat16(v.w);
    *(ushort4*)(wb + i) = cv.u;
}

// gather feat rows into bucket-contiguous order, fp32 -> bf16, once.
// one wave per output row (256 floats = 64 lanes x float4).
__global__ __launch_bounds__(256) void gather_kernel(
    const float* __restrict__ feat, const int* __restrict__ idxbuf,
    const int* __restrict__ cnt, ushort* __restrict__ gA, int P)
{
    int wid = threadIdx.x >> 6;
    int lane = threadIdx.x & 63;
    int slot = blockIdx.x * 4 + wid;
    if (slot >= P) return;
    int c0 = cnt[0], c1 = cnt[1], c2 = cnt[2];
    int b1 = c0, b2 = c0 + c1, b3 = c0 + c1 + c2;
    int f, i;
    if (slot < b1)      { f = 0; i = slot; }
    else if (slot < b2) { f = 1; i = slot - b1; }
    else if (slot < b3) { f = 2; i = slot - b2; }
    else                { f = 3; i = slot - b3; }
    int pid = idxbuf[f * P + i];
    float4 v = *(const float4*)(feat + (size_t)pid * C_IN + lane * 4);
    union { ushort4 u; __hip_bfloat16 h[4]; } cv;
    cv.h[0] = __float2bfloat16(v.x);
    cv.h[1] = __float2bfloat16(v.y);
    cv.h[2] = __float2bfloat16(v.z);
    cv.h[3] = __float2bfloat16(v.w);
    *(ushort4*)(gA + (size_t)slot * C_IN + lane * 4) = cv.u;
}

// stage K-step s (32 bf16 = 64 B per row) of A and B tiles into buffer b.
// Each 1KB gload_lds issue covers 16 rows x 64 B. Lane l: row seg*16+(l>>2),
// LDS chunk-slot l&3; source k-chunk pre-swizzled: c = (l&3) ^ ((l>>3)&3)
// (the involution p = c ^ ((row>>1)&3) with row>>1 == l>>3 within a segment).
#define STAGE32(s, b) do {                                                      \
    int kByte = (s) * 64;                                                       \
    _Pragma("unroll")                                                           \
    for (int n = 0; n < 2; ++n) {                                               \
        int seg = wid * 2 + n;              /* 0..7, 1 KB each */               \
        int row = seg * 16 + (lane >> 2);                                       \
        const char* srcA = aBase + ((size_t)(gBase + row) * (C_IN * 2))         \
                                 + kByte + schunk * 16;                         \
        __builtin_amdgcn_global_load_lds(                                       \
            (const __attribute__((address_space(1))) void*)srcA,                \
            (__attribute__((address_space(3))) void*)&sA[b][seg * 512], 16, 0, 0); \
        const char* srcB = bBase + ((size_t)(wRow0 + row) * (C_IN * 2))         \
                                 + kByte + schunk * 16;                         \
        __builtin_amdgcn_global_load_lds(                                       \
            (const __attribute__((address_space(1))) void*)srcB,                \
            (__attribute__((address_space(3))) void*)&sB[b][seg * 512], 16, 0, 0); \
    }                                                                           \
} while (0)

// dense bf16 GEMM over the gathered buffer: depth-1 double-buffered pipeline,
// FBK=32 -> 33 KB LDS -> 4 blocks/CU (16 waves/CU) so resident blocks cover
// each other's residual staging latency. One vmcnt(0)+barrier per K-step,
// issued AFTER the MFMAs so the prefetched stage overlaps compute.
__global__ __launch_bounds__(256, 4) void gemm_fast_kernel(
    const ushort* __restrict__ gA, const ushort* __restrict__ wb,
    const float* __restrict__ bias, const int* __restrict__ idxbuf,
    const int* __restrict__ cnt, float* __restrict__ out, int P)
{
    __shared__ ushort sA[2][BM * 32];   // 2 x 8 KB, linear (gload_lds dest)
    __shared__ ushort sB[2][BN * 32];   // 2 x 8 KB
    __shared__ int    sIdx[BM];
    __shared__ float  sBias[BN];

    // XCD-aware swizzle: 4 col-tiles of one row-tile land consecutively in
    // one XCD's round-robin stream. gridDim.x == 4, gridDim.y % 8 == 0.
    int lid = blockIdx.x + (blockIdx.y << 2);
    int g = lid & 7;
    int q = lid >> 3;
    int cTile = q & 3;
    int t = ((q >> 2) << 3) + g;

    int c0 = cnt[0], c1 = cnt[1], c2 = cnt[2], c3 = cnt[3];
    int counts[4] = {c0, c1, c2, c3};
    int bases[4]  = {0, c0, c0 + c1, c0 + c1 + c2};
    int f = -1, lt = 0;
    for (int ff = 0; ff < 4; ++ff) {
        int nt = (counts[ff] + BM - 1) / BM;
        if (t < nt) { f = ff; lt = t; break; }
        t -= nt;
    }
    if (f < 0) return;

    int tid = threadIdx.x;
    int oBase = cTile * BN;
    int cn = counts[f];
    int gBase = bases[f] + lt * BM;       // first gathered row of this tile
    int wRow0 = f * C_OUT + oBase;        // first weight row of this tile

    int wid = tid >> 6;
    int lane = tid & 63;
    int wm = (wid >> 1) * 64;
    int wn = (wid & 1) * 64;
    int lcol = lane & 15;
    int quad = lane >> 4;

    // read-side swizzled chunk (ushort units): for row r = wm+i*16+lcol,
    // (r>>1)&3 == (lcol>>1)&3 (wm, i*16 contribute 0 mod 8) -> lane-constant.
    int rchunk = (quad ^ ((lcol >> 1) & 3)) * 8;

    // staging source pre-swizzle (see STAGE32 comment)
    int schunk = (lane & 3) ^ ((lane >> 3) & 3);

    const char* aBase = (const char*)gA;
    const char* bBase = (const char*)wb;

    // prologue: issue stage 0, fill sIdx/sBias; __syncthreads drains
    // vmcnt+lgkmcnt -> stage 0 complete and visible.
    STAGE32(0, 0);
    if (tid < BM) {
        int r = lt * BM + tid;
        sIdx[tid] = (r < cn) ? idxbuf[f * P + r] : -1;
    }
    if (tid < BN) sBias[tid] = bias[f * C_OUT + oBase + tid];
    __syncthreads();

    floatx4 acc[4][4];
#pragma unroll
    for (int i = 0; i < 4; ++i)
#pragma unroll
        for (int j = 0; j < 4; ++j)
            acc[i][j] = (floatx4){0.f, 0.f, 0.f, 0.f};

#pragma unroll
    for (int s = 0; s < NSTEP; ++s) {
        if (s < NSTEP - 1) STAGE32(s + 1, (s + 1) & 1);   // depth-1 prefetch
        __builtin_amdgcn_sched_barrier(0);                 // keep issue order

        const ushort* cA = sA[s & 1];
        const ushort* cB = sB[s & 1];
        bf16x8 af[4], bfr[4];
#pragma unroll
        for (int i = 0; i < 4; ++i)
            af[i] = *(const bf16x8*)&cA[(wm + i * 16 + lcol) * 32 + rchunk];
#pragma unroll
        for (int j = 0; j < 4; ++j)
            bfr[j] = *(const bf16x8*)&cB[(wn + j * 16 + lcol) * 32 + rchunk];
#pragma unroll
        for (int i = 0; i < 4; ++i)
#pragma unroll
            for (int j = 0; j < 4; ++j)
                acc[i][j] = __builtin_amdgcn_mfma_f32_16x16x32_bf16(af[i], bfr[j], acc[i][j], 0, 0, 0);

        // wait for the prefetched stage (overlapped with the compute above),
        // then release both buffers. ds_reads completed before MFMAs (lgkm).
        asm volatile("s_waitcnt vmcnt(0)" ::: "memory");
        __builtin_amdgcn_s_barrier();
        __builtin_amdgcn_sched_barrier(0);
    }

    // epilogue: scatter rows by original point id, add bias
#pragma unroll
    for (int i = 0; i < 4; ++i) {
        int r0 = wm + i * 16 + quad * 4;
        int pid0 = sIdx[r0 + 0];
        int pid1 = sIdx[r0 + 1];
        int pid2 = sIdx[r0 + 2];
        int pid3 = sIdx[r0 + 3];
#pragma unroll
        for (int j = 0; j < 4; ++j) {
            int o = oBase + wn + j * 16 + lcol;
            float bv = sBias[wn + j * 16 + lcol];
            if (pid0 >= 0) out[pid0 * C_OUT + o] = acc[i][j][0] + bv;
            if (pid1 >= 0) out[pid1 * C_OUT + o] = acc[i][j][1] + bv;
            if (pid2 >= 0) out[pid2 * C_OUT + o] = acc[i][j][2] + bv;
            if (pid3 >= 0) out[pid3 * C_OUT + o] = acc[i][j][3] + bv;
        }
    }
}

// ---------------- fallback (old fused) gemm, used only if ws too small ----
__global__ __launch_bounds__(256) void gemm_kernel(
    const float* __restrict__ feat, const ushort* __restrict__ wb,
    const float* __restrict__ bias, const int* __restrict__ idxbuf,
    const int* __restrict__ cnt, float* __restrict__ out, int P)
{
    __shared__ ushort sA[BM * SAS];
    __shared__ ushort sB[BN * SAS];
    __shared__ int    sIdx[BM];
    __shared__ float  sBias[BN];

    int lid = blockIdx.x + (blockIdx.y << 2);
    int g = lid & 7;
    int q = lid >> 3;
    int cTile = q & 3;
    int t = ((q >> 2) << 3) + g;

    int counts[4];
    counts[0] = cnt[0]; counts[1] = cnt[1]; counts[2] = cnt[2]; counts[3] = cnt[3];
    int f = -1, lt = 0;
    for (int ff = 0; ff < 4; ++ff) {
        int nt = (counts[ff] + BM - 1) / BM;
        if (t < nt) { f = ff; lt = t; break; }
        t -= nt;
    }
    if (f < 0) return;

    int tid = threadIdx.x;
    int oBase = cTile * BN;
    int rowBase = lt * BM;
    int cn = counts[f];

    if (tid < BM) {
        int r = rowBase + tid;
        sIdx[tid] = (r < cn) ? idxbuf[f * P + r] : -1;
    }
    if (tid < BN) sBias[tid] = bias[f * C_OUT + oBase + tid];
    __syncthreads();

    int sRow = tid >> 1;
    int sHalf = tid & 1;
    int myIdx = sIdx[sRow];
    const float* aRow = feat + (size_t)(myIdx < 0 ? 0 : myIdx) * C_IN + sHalf * 16;
    const ushort* bRow = wb + (size_t)(f * C_OUT + oBase + sRow) * C_IN + sHalf * 16;

    int wid = tid >> 6;
    int lane = tid & 63;
    int wm = (wid >> 1) * 64;
    int wn = (wid & 1) * 64;
    int lcol = lane & 15;
    int quad = lane >> 4;

    floatx4 acc[4][4];
#pragma unroll
    for (int i = 0; i < 4; ++i)
#pragma unroll
        for (int j = 0; j < 4; ++j)
            acc[i][j] = (floatx4){0.f, 0.f, 0.f, 0.f};

    for (int kk = 0; kk < C_IN; kk += BK) {
        const float* ap = aRow + kk;
        float4 a0 = *(const float4*)(ap + 0);
        float4 a1 = *(const float4*)(ap + 4);
        float4 a2 = *(const float4*)(ap + 8);
        float4 a3 = *(const float4*)(ap + 12);
        const ushort* bp = bRow + kk;
        uint4 b01 = *(const uint4*)(bp + 0);
        uint4 b23 = *(const uint4*)(bp + 8);

        Pack8 p0, p1;
        p0.h[0] = __float2bfloat16(a0.x); p0.h[1] = __float2bfloat16(a0.y);
        p0.h[2] = __float2bfloat16(a0.z); p0.h[3] = __float2bfloat16(a0.w);
        p0.h[4] = __float2bfloat16(a1.x); p0.h[5] = __float2bfloat16(a1.y);
        p0.h[6] = __float2bfloat16(a1.z); p0.h[7] = __float2bfloat16(a1.w);
        p1.h[0] = __float2bfloat16(a2.x); p1.h[1] = __float2bfloat16(a2.y);
        p1.h[2] = __float2bfloat16(a2.z); p1.h[3] = __float2bfloat16(a2.w);
        p1.h[4] = __float2bfloat16(a3.x); p1.h[5] = __float2bfloat16(a3.y);
        p1.h[6] = __float2bfloat16(a3.z); p1.h[7] = __float2bfloat16(a3.w);

        ushort* dA = &sA[sRow * SAS + sHalf * 16];
        *(uint4*)(dA + 0) = p0.u;
        *(uint4*)(dA + 8) = p1.u;
        ushort* dB = &sB[sRow * SAS + sHalf * 16];
        *(uint4*)(dB + 0) = b01;
        *(uint4*)(dB + 8) = b23;

        __syncthreads();

        bf16x8 af[4], bfr[4];
#pragma unroll
        for (int i = 0; i < 4; ++i)
            af[i] = *(const bf16x8*)&sA[(wm + i * 16 + lcol) * SAS + quad * 8];
#pragma unroll
        for (int j = 0; j < 4; ++j)
            bfr[j] = *(const bf16x8*)&sB[(wn + j * 16 + lcol) * SAS + quad * 8];
#pragma unroll
        for (int i = 0; i < 4; ++i)
#pragma unroll
            for (int j = 0; j < 4; ++j)
                acc[i][j] = __builtin_amdgcn_mfma_f32_16x16x32_bf16(af[i], bfr[j], acc[i][j], 0, 0, 0);

        __syncthreads();
    }

#pragma unroll
    for (int i = 0; i < 4; ++i) {
        int r0 = wm + i * 16 + quad * 4;
        int pid0 = sIdx[r0 + 0];
        int pid1 = sIdx[r0 + 1];
        int pid2 = sIdx[r0 + 2];
        int pid3 = sIdx[r0 + 3];
#pragma unroll
        for (int j = 0; j < 4; ++j) {
            int o = oBase + wn + j * 16 + lcol;
            float bv = sBias[wn + j * 16 + lcol];
            if (pid0 >= 0) out[pid0 * C_OUT + o] = acc[i][j][0] + bv;
            if (pid1 >= 0) out[pid1 * C_OUT + o] = acc[i][j][1] + bv;
            if (pid2 >= 0) out[pid2 * C_OUT + o] = acc[i][j][2] + bv;
            if (pid3 >= 0) out[pid3 * C_OUT + o] = acc[i][j][3] + bv;
        }
    }
}

extern "C" void kernel_launch(void* const* d_in, const int* in_sizes, int n_in,
                              void* d_out, int out_size, void* d_ws, size_t ws_size,
                              hipStream_t stream) {
    const float* feat = (const float*)d_in[0];
    const float* xyz  = (const float*)d_in[1];
    const float* w    = (const float*)d_in[2];
    const float* bias = (const float*)d_in[3];
    float* out = (float*)d_out;
    int P = in_sizes[0] / C_IN;

    char* ws = (char*)d_ws;
    size_t offIdx = 0;
    size_t offCnt = (size_t)4 * P * 4;
    size_t offWb  = offCnt + 16;
    size_t offGA  = (offWb + (size_t)NFILT * C_OUT * C_IN * 2 + 255) & ~(size_t)255;
    size_t needed = offGA + (size_t)(P + BM) * C_IN * 2;   // +BM rows slack for padded tiles

    int* idxbuf = (int*)(ws + offIdx);
    int* cntp   = (int*)(ws + offCnt);
    ushort* wb  = (ushort*)(ws + offWb);

    // convert_w also zeroes cnt; stream order guarantees visibility
    convert_w_kernel<<<(NFILT * C_OUT * C_IN) / 1024, 256, 0, stream>>>(w, wb, cntp);
    bucketize_kernel<<<(P + 1023) / 1024, 1024, 0, stream>>>(xyz, idxbuf, cntp, P);

    int tilesY = ((P / BM + NFILT + 7) / 8) * 8;   // padded so XCD swizzle is bijective
    dim3 grid(C_OUT / BN, tilesY);

    if (ws_size >= needed) {
        ushort* gA = (ushort*)(ws + offGA);
        gather_kernel<<<(P + 3) / 4, 256, 0, stream>>>(feat, idxbuf, cntp, gA, P);
        gemm_fast_kernel<<<grid, 256, 0, stream>>>(gA, wb, bias, idxbuf, cntp, out, P);
    } else {
        gemm_kernel<<<grid, 256, 0, stream>>>(feat, wb, bias, idxbuf, cntp, out, P);
    }
}

// Round 5
// 236.475 us; speedup vs baseline: 1.0120x; 1.0120x over previous
//
#include <hip/hip_runtime.h>
#include <hip/hip_bf16.h>

#define C_IN   256
#define C_OUT  512
#define NFILT  4

#define BM 128
#define BN 128
#define BK 32
#define SAS 40   // old-path LDS row stride

// fast path geometry: 32 bf16 per K-step, 8 steps, 4-buffer ring
#define NSTEP 8

typedef __attribute__((ext_vector_type(8))) short bf16x8;
typedef __attribute__((ext_vector_type(4))) float floatx4;

union Pack8 { uint4 u; __hip_bfloat16 h[8]; };

// ---- bucketize: per-block LDS histogram, 4 global atomics per block ----
__global__ __launch_bounds__(1024) void bucketize_kernel(
    const float* __restrict__ xyz, int* __restrict__ idxbuf,
    int* __restrict__ cnt, int P)
{
    __shared__ int hist[NFILT];        // block totals
    __shared__ int wbase[16][NFILT];   // per-wave base within block
    __shared__ int gbase[NFILT];       // block's global base per filter

    int tid = threadIdx.x;
    int wid = tid >> 6;
    int lane = tid & 63;
    if (tid < NFILT) hist[tid] = 0;
    __syncthreads();

    int pid = blockIdx.x * 1024 + tid;
    int filt = -1;
    if (pid < P) {
        float x = xyz[pid * 3 + 0];
        float y = xyz[pid * 3 + 1];
        float z = xyz[pid * 3 + 2];
        // match np: non-fused fp32 sum of squares, then sqrt, then strict <
        float r2 = __fadd_rn(__fadd_rn(__fmul_rn(x, x), __fmul_rn(y, y)), __fmul_rn(z, z));
        float r = sqrtf(r2);
        if (r < 1.0f)        filt = 0;
        else if (r < 1.5f)   filt = 1;
        else if (r < 2.0f)   filt = 2;
        else if (r < 100.0f) filt = 3;
        else                 filt = 0;   // argmax over all-false booleans returns 0
    }

    int myoff = 0;
#pragma unroll
    for (int f = 0; f < NFILT; ++f) {
        unsigned long long m = __ballot(filt == f);
        if (lane == 0) wbase[wid][f] = atomicAdd(&hist[f], (int)__popcll(m));
        if (filt == f) myoff = __popcll(m & ((1ull << lane) - 1ull));
    }
    __syncthreads();
    if (tid < NFILT) gbase[tid] = atomicAdd(&cnt[tid], hist[tid]);
    __syncthreads();

    if (filt >= 0)
        idxbuf[filt * P + gbase[filt] + wbase[wid][filt] + myoff] = pid;
}

// also zeroes cnt (runs before bucketize on the same stream)
__global__ void convert_w_kernel(const float* __restrict__ w,
                                 ushort* __restrict__ wb,
                                 int* __restrict__ cnt) {
    if (blockIdx.x == 0 && threadIdx.x < NFILT) cnt[threadIdx.x] = 0;
    int i = (blockIdx.x * blockDim.x + threadIdx.x) * 4;
    float4 v = *(const float4*)(w + i);
    union { ushort4 u; __hip_bfloat16 h[4]; } cv;
    cv.h[0] = __float2bfloat16(v.x);
    cv.h[1] = __float2bfloat16(v.y);
    cv.h[2] = __float2bfloat16(v.z);
    cv.h[3] = __float2bfloat16(v.w);
    *(ushort4*)(wb + i) = cv.u;
}

// gather feat rows into bucket-contiguous order, fp32 -> bf16, once.
// one wave per output row (256 floats = 64 lanes x float4).
__global__ __launch_bounds__(256) void gather_kernel(
    const float* __restrict__ feat, const int* __restrict__ idxbuf,
    const int* __restrict__ cnt, ushort* __restrict__ gA, int P)
{
    int wid = threadIdx.x >> 6;
    int lane = threadIdx.x & 63;
    int slot = blockIdx.x * 4 + wid;
    if (slot >= P) return;
    int c0 = cnt[0], c1 = cnt[1], c2 = cnt[2];
    int b1 = c0, b2 = c0 + c1, b3 = c0 + c1 + c2;
    int f, i;
    if (slot < b1)      { f = 0; i = slot; }
    else if (slot < b2) { f = 1; i = slot - b1; }
    else if (slot < b3) { f = 2; i = slot - b2; }
    else                { f = 3; i = slot - b3; }
    int pid = idxbuf[f * P + i];
    float4 v = *(const float4*)(feat + (size_t)pid * C_IN + lane * 4);
    union { ushort4 u; __hip_bfloat16 h[4]; } cv;
    cv.h[0] = __float2bfloat16(v.x);
    cv.h[1] = __float2bfloat16(v.y);
    cv.h[2] = __float2bfloat16(v.z);
    cv.h[3] = __float2bfloat16(v.w);
    *(ushort4*)(gA + (size_t)slot * C_IN + lane * 4) = cv.u;
}

// stage K-step s (32 bf16 = 64 B per row) of A and B tiles into ring buffer b.
// Each 1KB gload_lds issue covers 16 rows x 64 B. Lane l: row seg*16+(l>>2),
// LDS chunk-slot l&3; source k-chunk pre-swizzled: c = (l&3) ^ ((l>>3)&3)
// (the involution p = c ^ ((row>>1)&3) with row>>1 == l>>3 within a segment).
#define STAGE32(s, b) do {                                                      \
    int kByte = (s) * 64;                                                       \
    _Pragma("unroll")                                                           \
    for (int n = 0; n < 2; ++n) {                                               \
        int seg = wid * 2 + n;              /* 0..7, 1 KB each */               \
        int row = seg * 16 + (lane >> 2);                                       \
        const char* srcA = aBase + ((size_t)(gBase + row) * (C_IN * 2))         \
                                 + kByte + schunk * 16;                         \
        __builtin_amdgcn_global_load_lds(                                       \
            (const __attribute__((address_space(1))) void*)srcA,                \
            (__attribute__((address_space(3))) void*)&sA[b][seg * 512], 16, 0, 0); \
        const char* srcB = bBase + ((size_t)(wRow0 + row) * (C_IN * 2))         \
                                 + kByte + schunk * 16;                         \
        __builtin_amdgcn_global_load_lds(                                       \
            (const __attribute__((address_space(1))) void*)srcB,                \
            (__attribute__((address_space(3))) void*)&sB[b][seg * 512], 16, 0, 0); \
    }                                                                           \
} while (0)

// dense bf16 GEMM over the gathered buffer: 4-buffer ring, depth-3 stage
// issue, COUNTED vmcnt (T4 — never drain to 0 in the main loop), one barrier
// per K-step. Each stage has ~3 steps of lead time, so HBM latency is fully
// covered even at 2 blocks/CU.
__global__ __launch_bounds__(256, 2) void gemm_fast_kernel(
    const ushort* __restrict__ gA, const ushort* __restrict__ wb,
    const float* __restrict__ bias, const int* __restrict__ idxbuf,
    const int* __restrict__ cnt, float* __restrict__ out, int P)
{
    __shared__ ushort sA[4][BM * 32];   // 4 x 8 KB ring, linear (gload_lds dest)
    __shared__ ushort sB[4][BN * 32];   // 4 x 8 KB ring
    __shared__ int    sIdx[BM];
    __shared__ float  sBias[BN];

    // XCD-aware swizzle: 4 col-tiles of one row-tile land consecutively in
    // one XCD's round-robin stream. gridDim.x == 4, gridDim.y % 8 == 0.
    int lid = blockIdx.x + (blockIdx.y << 2);
    int g = lid & 7;
    int q = lid >> 3;
    int cTile = q & 3;
    int t = ((q >> 2) << 3) + g;

    int c0 = cnt[0], c1 = cnt[1], c2 = cnt[2], c3 = cnt[3];
    int counts[4] = {c0, c1, c2, c3};
    int bases[4]  = {0, c0, c0 + c1, c0 + c1 + c2};
    int f = -1, lt = 0;
    for (int ff = 0; ff < 4; ++ff) {
        int nt = (counts[ff] + BM - 1) / BM;
        if (t < nt) { f = ff; lt = t; break; }
        t -= nt;
    }
    if (f < 0) return;

    int tid = threadIdx.x;
    int oBase = cTile * BN;
    int cn = counts[f];
    int gBase = bases[f] + lt * BM;       // first gathered row of this tile
    int wRow0 = f * C_OUT + oBase;        // first weight row of this tile

    int wid = tid >> 6;
    int lane = tid & 63;
    int wm = (wid >> 1) * 64;
    int wn = (wid & 1) * 64;
    int lcol = lane & 15;
    int quad = lane >> 4;

    // read-side swizzled chunk (ushort units): for row r = wm+i*16+lcol,
    // (r>>1)&3 == (lcol>>1)&3 (wm, i*16 contribute 0 mod 8) -> lane-constant.
    int rchunk = (quad ^ ((lcol >> 1) & 3)) * 8;

    // staging source pre-swizzle (see STAGE32 comment)
    int schunk = (lane & 3) ^ ((lane >> 3) & 3);

    const char* aBase = (const char*)gA;
    const char* bBase = (const char*)wb;

    // prologue: issue stages 0..2, fill sIdx/sBias; __syncthreads drains
    // vmcnt+lgkmcnt -> stages 0..2 complete, pipeline refills in-loop.
    STAGE32(0, 0);
    STAGE32(1, 1);
    STAGE32(2, 2);
    if (tid < BM) {
        int r = lt * BM + tid;
        sIdx[tid] = (r < cn) ? idxbuf[f * P + r] : -1;
    }
    if (tid < BN) sBias[tid] = bias[f * C_OUT + oBase + tid];
    __syncthreads();

    floatx4 acc[4][4];
#pragma unroll
    for (int i = 0; i < 4; ++i)
#pragma unroll
        for (int j = 0; j < 4; ++j)
            acc[i][j] = (floatx4){0.f, 0.f, 0.f, 0.f};

#pragma unroll
    for (int s = 0; s < NSTEP; ++s) {
        // certify OWN stage-s loads done (4 loads per outstanding stage);
        // tail steps have fewer stages in flight.
        if (NSTEP - 1 - s >= 2)      asm volatile("s_waitcnt vmcnt(8)" ::: "memory");
        else if (NSTEP - 1 - s == 1) asm volatile("s_waitcnt vmcnt(4)" ::: "memory");
        else                         asm volatile("s_waitcnt vmcnt(0)" ::: "memory");
        // publish: after this barrier, every wave's stage-s loads are in LDS,
        // and every wave finished reading buffer (s+3)&3 (= (s-1)&3).
        __builtin_amdgcn_s_barrier();
        __builtin_amdgcn_sched_barrier(0);   // barrier builtin is not a code-motion fence

        if (s + 3 < NSTEP) STAGE32(s + 3, (s + 3) & 3);   // refill freed buffer

        const ushort* cA = sA[s & 3];
        const ushort* cB = sB[s & 3];
        bf16x8 af[4], bfr[4];
#pragma unroll
        for (int i = 0; i < 4; ++i)
            af[i] = *(const bf16x8*)&cA[(wm + i * 16 + lcol) * 32 + rchunk];
#pragma unroll
        for (int j = 0; j < 4; ++j)
            bfr[j] = *(const bf16x8*)&cB[(wn + j * 16 + lcol) * 32 + rchunk];
#pragma unroll
        for (int i = 0; i < 4; ++i)
#pragma unroll
            for (int j = 0; j < 4; ++j)
                acc[i][j] = __builtin_amdgcn_mfma_f32_16x16x32_bf16(af[i], bfr[j], acc[i][j], 0, 0, 0);
        // all ds_read results are consumed by MFMAs (compiler inserts lgkm
        // waits), so crossing the next barrier cannot expose a stale read.
    }

    // epilogue: scatter rows by original point id, add bias
#pragma unroll
    for (int i = 0; i < 4; ++i) {
        int r0 = wm + i * 16 + quad * 4;
        int pid0 = sIdx[r0 + 0];
        int pid1 = sIdx[r0 + 1];
        int pid2 = sIdx[r0 + 2];
        int pid3 = sIdx[r0 + 3];
#pragma unroll
        for (int j = 0; j < 4; ++j) {
            int o = oBase + wn + j * 16 + lcol;
            float bv = sBias[wn + j * 16 + lcol];
            if (pid0 >= 0) out[pid0 * C_OUT + o] = acc[i][j][0] + bv;
            if (pid1 >= 0) out[pid1 * C_OUT + o] = acc[i][j][1] + bv;
            if (pid2 >= 0) out[pid2 * C_OUT + o] = acc[i][j][2] + bv;
            if (pid3 >= 0) out[pid3 * C_OUT + o] = acc[i][j][3] + bv;
        }
    }
}

// ---------------- fallback (old fused) gemm, used only if ws too small ----
__global__ __launch_bounds__(256) void gemm_kernel(
    const float* __restrict__ feat, const ushort* __restrict__ wb,
    const float* __restrict__ bias, const int* __restrict__ idxbuf,
    const int* __restrict__ cnt, float* __restrict__ out, int P)
{
    __shared__ ushort sA[BM * SAS];
    __shared__ ushort sB[BN * SAS];
    __shared__ int    sIdx[BM];
    __shared__ float  sBias[BN];

    int lid = blockIdx.x + (blockIdx.y << 2);
    int g = lid & 7;
    int q = lid >> 3;
    int cTile = q & 3;
    int t = ((q >> 2) << 3) + g;

    int counts[4];
    counts[0] = cnt[0]; counts[1] = cnt[1]; counts[2] = cnt[2]; counts[3] = cnt[3];
    int f = -1, lt = 0;
    for (int ff = 0; ff < 4; ++ff) {
        int nt = (counts[ff] + BM - 1) / BM;
        if (t < nt) { f = ff; lt = t; break; }
        t -= nt;
    }
    if (f < 0) return;

    int tid = threadIdx.x;
    int oBase = cTile * BN;
    int rowBase = lt * BM;
    int cn = counts[f];

    if (tid < BM) {
        int r = rowBase + tid;
        sIdx[tid] = (r < cn) ? idxbuf[f * P + r] : -1;
    }
    if (tid < BN) sBias[tid] = bias[f * C_OUT + oBase + tid];
    __syncthreads();

    int sRow = tid >> 1;
    int sHalf = tid & 1;
    int myIdx = sIdx[sRow];
    const float* aRow = feat + (size_t)(myIdx < 0 ? 0 : myIdx) * C_IN + sHalf * 16;
    const ushort* bRow = wb + (size_t)(f * C_OUT + oBase + sRow) * C_IN + sHalf * 16;

    int wid = tid >> 6;
    int lane = tid & 63;
    int wm = (wid >> 1) * 64;
    int wn = (wid & 1) * 64;
    int lcol = lane & 15;
    int quad = lane >> 4;

    floatx4 acc[4][4];
#pragma unroll
    for (int i = 0; i < 4; ++i)
#pragma unroll
        for (int j = 0; j < 4; ++j)
            acc[i][j] = (floatx4){0.f, 0.f, 0.f, 0.f};

    for (int kk = 0; kk < C_IN; kk += BK) {
        const float* ap = aRow + kk;
        float4 a0 = *(const float4*)(ap + 0);
        float4 a1 = *(const float4*)(ap + 4);
        float4 a2 = *(const float4*)(ap + 8);
        float4 a3 = *(const float4*)(ap + 12);
        const ushort* bp = bRow + kk;
        uint4 b01 = *(const uint4*)(bp + 0);
        uint4 b23 = *(const uint4*)(bp + 8);

        Pack8 p0, p1;
        p0.h[0] = __float2bfloat16(a0.x); p0.h[1] = __float2bfloat16(a0.y);
        p0.h[2] = __float2bfloat16(a0.z); p0.h[3] = __float2bfloat16(a0.w);
        p0.h[4] = __float2bfloat16(a1.x); p0.h[5] = __float2bfloat16(a1.y);
        p0.h[6] = __float2bfloat16(a1.z); p0.h[7] = __float2bfloat16(a1.w);
        p1.h[0] = __float2bfloat16(a2.x); p1.h[1] = __float2bfloat16(a2.y);
        p1.h[2] = __float2bfloat16(a2.z); p1.h[3] = __float2bfloat16(a2.w);
        p1.h[4] = __float2bfloat16(a3.x); p1.h[5] = __float2bfloat16(a3.y);
        p1.h[6] = __float2bfloat16(a3.z); p1.h[7] = __float2bfloat16(a3.w);

        ushort* dA = &sA[sRow * SAS + sHalf * 16];
        *(uint4*)(dA + 0) = p0.u;
        *(uint4*)(dA + 8) = p1.u;
        ushort* dB = &sB[sRow * SAS + sHalf * 16];
        *(uint4*)(dB + 0) = b01;
        *(uint4*)(dB + 8) = b23;

        __syncthreads();

        bf16x8 af[4], bfr[4];
#pragma unroll
        for (int i = 0; i < 4; ++i)
            af[i] = *(const bf16x8*)&sA[(wm + i * 16 + lcol) * SAS + quad * 8];
#pragma unroll
        for (int j = 0; j < 4; ++j)
            bfr[j] = *(const bf16x8*)&sB[(wn + j * 16 + lcol) * SAS + quad * 8];
#pragma unroll
        for (int i = 0; i < 4; ++i)
#pragma unroll
            for (int j = 0; j < 4; ++j)
                acc[i][j] = __builtin_amdgcn_mfma_f32_16x16x32_bf16(af[i], bfr[j], acc[i][j], 0, 0, 0);

        __syncthreads();
    }

#pragma unroll
    for (int i = 0; i < 4; ++i) {
        int r0 = wm + i * 16 + quad * 4;
        int pid0 = sIdx[r0 + 0];
        int pid1 = sIdx[r0 + 1];
        int pid2 = sIdx[r0 + 2];
        int pid3 = sIdx[r0 + 3];
#pragma unroll
        for (int j = 0; j < 4; ++j) {
            int o = oBase + wn + j * 16 + lcol;
            float bv = sBias[wn + j * 16 + lcol];
            if (pid0 >= 0) out[pid0 * C_OUT + o] = acc[i][j][0] + bv;
            if (pid1 >= 0) out[pid1 * C_OUT + o] = acc[i][j][1] + bv;
            if (pid2 >= 0) out[pid2 * C_OUT + o] = acc[i][j][2] + bv;
            if (pid3 >= 0) out[pid3 * C_OUT + o] = acc[i][j][3] + bv;
        }
    }
}

extern "C" void kernel_launch(void* const* d_in, const int* in_sizes, int n_in,
                              void* d_out, int out_size, void* d_ws, size_t ws_size,
                              hipStream_t stream) {
    const float* feat = (const float*)d_in[0];
    const float* xyz  = (const float*)d_in[1];
    const float* w    = (const float*)d_in[2];
    const float* bias = (const float*)d_in[3];
    float* out = (float*)d_out;
    int P = in_sizes[0] / C_IN;

    char* ws = (char*)d_ws;
    size_t offIdx = 0;
    size_t offCnt = (size_t)4 * P * 4;
    size_t offWb  = offCnt + 16;
    size_t offGA  = (offWb + (size_t)NFILT * C_OUT * C_IN * 2 + 255) & ~(size_t)255;
    size_t needed = offGA + (size_t)(P + BM) * C_IN * 2;   // +BM rows slack for padded tiles

    int* idxbuf = (int*)(ws + offIdx);
    int* cntp   = (int*)(ws + offCnt);
    ushort* wb  = (ushort*)(ws + offWb);

    // convert_w also zeroes cnt; stream order guarantees visibility
    convert_w_kernel<<<(NFILT * C_OUT * C_IN) / 1024, 256, 0, stream>>>(w, wb, cntp);
    bucketize_kernel<<<(P + 1023) / 1024, 1024, 0, stream>>>(xyz, idxbuf, cntp, P);

    int tilesY = ((P / BM + NFILT + 7) / 8) * 8;   // padded so XCD swizzle is bijective
    dim3 grid(C_OUT / BN, tilesY);

    if (ws_size >= needed) {
        ushort* gA = (ushort*)(ws + offGA);
        gather_kernel<<<(P + 3) / 4, 256, 0, stream>>>(feat, idxbuf, cntp, gA, P);
        gemm_fast_kernel<<<grid, 256, 0, stream>>>(gA, wb, bias, idxbuf, cntp, out, P);
    } else {
        gemm_kernel<<<grid, 256, 0, stream>>>(feat, wb, bias, idxbuf, cntp, out, P);
    }
}